// Round 5
// baseline (121.668 us; speedup 1.0000x reference)
//
#include <hip/hip_runtime.h>

// QTT 3D sampling, round 14: safe 2-dispatch pipeline, no U table, no
// transpose producers, no inter-block handshakes (round-13 rollback).
//   K1 (321 blocks):
//     bx 0      : counting sort of samples by d4 (perms/bases)
//     bx 1-64   : T[q][s5] = C5·(C6·C7)            (512 x 256 table)
//     bx 65-320 : P3 = C0·C1·C2·C3, block=(d0,d2pair,d3), M=16 rows
//                 (d2sub,d1) built in-LDS, then K=256 GEMM vs C3[d3].
//   K2 (8 x 32 blocks): per d4-group of sorted samples, tiles of 16:
//     A = gather 16 P3 rows (prefix digits), B = C4_d4 k-rows streamed
//     (contiguous, no transpose), K=256 GEMM; fused epilogue
//     out[i] = dot(V4row, T[suffix3]) + wave shfl reduce.
//   Both GEMMs: barrier-free per-wave K-split (wave w owns K in
//   [64w,64w+64), private dbuf B stage, counted vmcnt(4), no main-loop
//   barriers), two-phase 4-way cross-wave reduce through dead Bs region.
// Core shapes: (r_l, 8, r_{l+1}), ranks 1,8,64,256,256,256,64,8,1.
// C_l[k][d][s] at C_l[k*8*r_out + d*r_out + s].

typedef unsigned int u32;

__device__ __forceinline__ void async_load16(const float* g, float* l) {
    __builtin_amdgcn_global_load_lds(
        (const __attribute__((address_space(1))) u32*)g,
        (__attribute__((address_space(3))) u32*)l, 16, 0, 0);
}
__device__ __forceinline__ void fma4(float4& c, float a, const float4& b) {
    c.x = fmaf(a, b.x, c.x); c.y = fmaf(a, b.y, c.y);
    c.z = fmaf(a, b.z, c.z); c.w = fmaf(a, b.w, c.w);
}
__device__ __forceinline__ int digit_of(int x, int y, int z, int sh) {
    return 4*((x>>sh)&1) + 2*((y>>sh)&1) + ((z>>sh)&1);
}

// Barrier-free K-split GEMM, M=16 rows x 256 cols, K=256 split 64/wave.
// Caller prefetched this wave's chunk-0 into BsF[wv*2048..] and staged As,
// then __syncthreads()'d. Output row for r: rowBase + mulLo*(r&7) + 8*(r>>3).
__device__ __forceinline__ void kgemm16(
    const float* __restrict__ Cd, int rowStride,
    const float (*As)[260], float* BsF,
    float* __restrict__ outP, int rowBase, int mulLo,
    int ln, int wv)
{
    const int kbase = wv * 64;
    float4 acc[16];
#pragma unroll
    for (int r = 0; r < 16; ++r) acc[r] = make_float4(0,0,0,0);

#pragma unroll 1
    for (int s = 0; s < 16; ++s) {
        if (s < 15) {
            const int nb = (s + 1) & 1;
            const int ko = kbase + (s + 1) * 4;
#pragma unroll
            for (int j = 0; j < 4; ++j)
                async_load16(Cd + (size_t)(ko + j)*rowStride + ln*4,
                             BsF + wv*2048 + nb*1024 + j*256 + ln*4);
            asm volatile("s_waitcnt vmcnt(4)" ::: "memory");
        } else {
            asm volatile("s_waitcnt vmcnt(0)" ::: "memory");
        }
        __builtin_amdgcn_sched_barrier(0);
        const int cb = s & 1, kb = kbase + s * 4;
        const float* Bp = BsF + wv*2048 + cb*1024;
        const float4 b0v = *(const float4*)(Bp +   0 + ln*4);
        const float4 b1v = *(const float4*)(Bp + 256 + ln*4);
        const float4 b2v = *(const float4*)(Bp + 512 + ln*4);
        const float4 b3v = *(const float4*)(Bp + 768 + ln*4);
#pragma unroll
        for (int r = 0; r < 16; ++r) {
            const float4 a = *(const float4*)&As[r][kb];
            fma4(acc[r], a.x, b0v); fma4(acc[r], a.y, b1v);
            fma4(acc[r], a.z, b2v); fma4(acc[r], a.w, b3v);
        }
    }

    // two-phase cross-wave reduce through the (now dead) Bs region
#pragma unroll
    for (int ph = 0; ph < 2; ++ph) {
        float* my = BsF + wv * 2048;
#pragma unroll
        for (int r8 = 0; r8 < 8; ++r8)
            *(float4*)(my + r8*256 + ln*4) = acc[ph*8 + r8];
        __syncthreads();
#pragma unroll
        for (int i = 0; i < 2; ++i) {
            const int rr = wv*2 + i;
            float4 v        = *(const float4*)(BsF +        rr*256 + ln*4);
            const float4 p1 = *(const float4*)(BsF + 2048 + rr*256 + ln*4);
            const float4 p2 = *(const float4*)(BsF + 4096 + rr*256 + ln*4);
            const float4 p3 = *(const float4*)(BsF + 6144 + rr*256 + ln*4);
            v.x += p1.x + p2.x + p3.x; v.y += p1.y + p2.y + p3.y;
            v.z += p1.z + p2.z + p3.z; v.w += p1.w + p2.w + p3.w;
            const int r = ph*8 + rr;
            const int row = rowBase + mulLo*(r & 7) + 8*(r >> 3);
            *(float4*)(outP + (size_t)row*256 + ln*4) = v;
        }
        __syncthreads();
    }
}

// ---------------- K1: sort + T table + dense P3 table ------------------------
__global__ __launch_bounds__(256, 3) void tables_kernel(
    const float* __restrict__ C0, const float* __restrict__ C1,
    const float* __restrict__ C2, const float* __restrict__ C3,
    const float* __restrict__ C5, const float* __restrict__ C6,
    const float* __restrict__ C7,
    const int* __restrict__ coords, int n,
    int* __restrict__ perms, int* __restrict__ bases,
    float* __restrict__ P3, float* __restrict__ T)
{
    __shared__ __align__(16) union {
        struct { unsigned char digs[8192]; int cnt[8]; int offs[8]; } p;
        struct { float S6s[8][64]; } b;
        struct { float v64[8][64]; float As[16][260]; float Bs[4][2][4][256]; } g;
    } u;                                       // 50.3 KB -> 3 blocks/CU
    const int t = threadIdx.x;
    const int ln = t & 63, wv = t >> 6;
    const int bx = blockIdx.x;

    if (bx == 0) {
        // ---- counting sort by d4 (shift 3) ----
        if (t < 8) u.p.cnt[t] = 0;
        __syncthreads();
        for (int i = t; i < n; i += 256) {
            const int d = digit_of(coords[3*i], coords[3*i+1], coords[3*i+2], 3);
            u.p.digs[i] = (unsigned char)d;
            atomicAdd(&u.p.cnt[d], 1);
        }
        __syncthreads();
        if (t == 0) {
            int run = 0;
            for (int d = 0; d < 8; ++d) {
                u.p.offs[d] = run;
                bases[d] = run;
                run += u.p.cnt[d];
            }
            bases[8] = run;
        }
        __syncthreads();
        for (int i = t; i < n; i += 256) {
            const int pos = atomicAdd(&u.p.offs[u.p.digs[i]], 1);
            perms[pos] = i;
        }
    } else if (bx < 65) {
        // ---- T table: block = (d5, d6), all 8 d7; thread t = s5 ----
        const int bb = bx - 1;
        const int d5 = bb >> 3, d6 = bb & 7;
#pragma unroll
        for (int j = 0; j < 2; ++j) {
            const int idx = t + 256*j, d7 = idx >> 6, s = idx & 63;
            float acc = 0.f;
#pragma unroll
            for (int jj = 0; jj < 8; ++jj)
                acc = fmaf(C6[s*64 + d6*8 + jj], C7[jj*8 + d7], acc);
            u.b.S6s[d7][s] = acc;
        }
        __syncthreads();
        float4 creg[16];
#pragma unroll
        for (int s4 = 0; s4 < 16; ++s4)
            creg[s4] = *(const float4*)(C5 + (size_t)t*512 + d5*64 + s4*4);
#pragma unroll 1
        for (int d7 = 0; d7 < 8; ++d7) {
            float acc = 0.f;
#pragma unroll
            for (int s4 = 0; s4 < 16; ++s4) {
                const float4 a = creg[s4];
                const float4 b = *(const float4*)&u.b.S6s[d7][s4*4];
                acc = fmaf(a.x, b.x, acc); acc = fmaf(a.y, b.y, acc);
                acc = fmaf(a.z, b.z, acc); acc = fmaf(a.w, b.w, acc);
            }
            T[(size_t)((d5*8 + d6)*8 + d7)*256 + t] = acc;
        }
    } else {
        // ---- P3 block: (d0, d2pair, d3); 16 rows = (d2sub, d1) ----
        const int bb = bx - 65;
        const int d3 = bb & 7, d2p = (bb >> 3) & 3, d0 = bb >> 5;
        const float* Cd = C3 + d3 * 256;       // row k at Cd + k*2048
        float* BsF = &u.g.Bs[0][0][0][0];
        const int kbase = wv * 64;

        // prefetch this wave's chunk-0 B rows
#pragma unroll
        for (int j = 0; j < 4; ++j)
            async_load16(Cd + (size_t)(kbase + j)*2048 + ln*4,
                         BsF + wv*2048 + j*256 + ln*4);

        // v64[d1][c] = sum_r C0[d0,r] * C1[r, d1, c]
#pragma unroll
        for (int j = 0; j < 2; ++j) {
            const int idx = t + 256*j, d1 = idx >> 6, c = idx & 63;
            float acc = 0.f;
#pragma unroll
            for (int r = 0; r < 8; ++r)
                acc = fmaf(C0[d0*8 + r], C1[r*512 + d1*64 + c], acc);
            u.g.v64[d1][c] = acc;
        }
        __syncthreads();

        // As[r][k] = sum_j v64[d1(r)][j] * C2[j, d2(r), k]
        // wave wv builds rows wv*4 .. wv*4+3 (shared d2 = d2p*2 + (wv>>1))
        {
            const int rbase = wv * 4;
            const int d2 = d2p*2 + (rbase >> 3);
            float4 a0 = make_float4(0,0,0,0), a1 = make_float4(0,0,0,0);
            float4 a2 = make_float4(0,0,0,0), a3 = make_float4(0,0,0,0);
#pragma unroll 8
            for (int j = 0; j < 64; ++j) {
                const float4 c2 = *(const float4*)(C2 + (size_t)j*2048 + d2*256 + ln*4);
                fma4(a0, u.g.v64[(rbase+0)&7][j], c2);
                fma4(a1, u.g.v64[(rbase+1)&7][j], c2);
                fma4(a2, u.g.v64[(rbase+2)&7][j], c2);
                fma4(a3, u.g.v64[(rbase+3)&7][j], c2);
            }
            *(float4*)&u.g.As[rbase+0][ln*4] = a0;
            *(float4*)&u.g.As[rbase+1][ln*4] = a1;
            *(float4*)&u.g.As[rbase+2][ln*4] = a2;
            *(float4*)&u.g.As[rbase+3][ln*4] = a3;
        }
        __syncthreads();                       // As + everyone's chunk0 ready

        // row = d0*512 + d1*64 + d2*8 + d3, d1 = r&7, d2 = d2p*2 + (r>>3)
        kgemm16(Cd, 2048, u.g.As, BsF, P3, d0*512 + d2p*16 + d3, 64, ln, wv);
    }
}

// ---------------- K2: d4-grouped gather-GEMM + fused final -------------------
__global__ __launch_bounds__(256, 3) void stage4_final_kernel(
    const float* __restrict__ P3, const float* __restrict__ C4,
    const float* __restrict__ T, const int* __restrict__ coords,
    const int* __restrict__ perm, const int* __restrict__ base,
    float* __restrict__ out)
{
    const int d = blockIdx.x;
    const int b0 = base[d], b1 = base[d + 1];
    const int nrows = b1 - b0;
    const int t = threadIdx.x, ln = t & 63, wv = t >> 6;

    __shared__ __align__(16) float As[16][260];
    __shared__ __align__(16) float Bs[4][2][4][256];
    __shared__ int rows[16], aidx[16], qs[16];
    float* BsF = &Bs[0][0][0][0];

    const float* Cd = C4 + d * 256;            // row k at Cd + k*2048
    const int kbase = wv * 64;

    for (int tile = blockIdx.y; tile * 16 < nrows; tile += (int)gridDim.y) {
        const int row0 = b0 + tile * 16;

        // prefetch this wave's chunk-0 B rows
#pragma unroll
        for (int j = 0; j < 4; ++j)
            async_load16(Cd + (size_t)(kbase + j)*2048 + ln*4,
                         BsF + wv*2048 + j*256 + ln*4);

        if (t < 16) {
            const int gr = row0 + t;
            const int rr = (gr < b1) ? perm[gr] : -1;
            rows[t] = rr;
            int a = 0, q = 0;
            if (rr >= 0) {
                const int x = coords[3*rr], y = coords[3*rr+1], z = coords[3*rr+2];
                a = digit_of(x,y,z,7)*512 + digit_of(x,y,z,6)*64
                  + digit_of(x,y,z,5)*8 + digit_of(x,y,z,4);
                q = digit_of(x,y,z,2)*64 + digit_of(x,y,z,1)*8 + digit_of(x,y,z,0);
            }
            aidx[t] = a; qs[t] = q;
        }
        __syncthreads();

        // gather A (16 x 256) from P3 prefix rows: 1024 f4, 4/thread
#pragma unroll
        for (int j = 0; j < 4; ++j) {
            const int idx = t + 256*j, s = idx >> 6, c4 = idx & 63;
            float4 v = make_float4(0,0,0,0);
            if (rows[s] >= 0)
                v = *(const float4*)(P3 + (size_t)aidx[s]*256 + c4*4);
            *(float4*)&As[s][c4*4] = v;
        }
        __syncthreads();                       // As + everyone's chunk0 ready

        // main GEMM: barrier-free per-wave K-split (V4[s][s5] accumulate)
        float4 acc[16];
#pragma unroll
        for (int r = 0; r < 16; ++r) acc[r] = make_float4(0,0,0,0);

#pragma unroll 1
        for (int s = 0; s < 16; ++s) {
            if (s < 15) {
                const int nb = (s + 1) & 1;
                const int ko = kbase + (s + 1) * 4;
#pragma unroll
                for (int j = 0; j < 4; ++j)
                    async_load16(Cd + (size_t)(ko + j)*2048 + ln*4,
                                 BsF + wv*2048 + nb*1024 + j*256 + ln*4);
                asm volatile("s_waitcnt vmcnt(4)" ::: "memory");
            } else {
                asm volatile("s_waitcnt vmcnt(0)" ::: "memory");
            }
            __builtin_amdgcn_sched_barrier(0);
            const int cb = s & 1, kb = kbase + s * 4;
            const float* Bp = BsF + wv*2048 + cb*1024;
            const float4 b0v = *(const float4*)(Bp +   0 + ln*4);
            const float4 b1v = *(const float4*)(Bp + 256 + ln*4);
            const float4 b2v = *(const float4*)(Bp + 512 + ln*4);
            const float4 b3v = *(const float4*)(Bp + 768 + ln*4);
#pragma unroll
            for (int r = 0; r < 16; ++r) {
                const float4 a = *(const float4*)&As[r][kb];
                fma4(acc[r], a.x, b0v); fma4(acc[r], a.y, b1v);
                fma4(acc[r], a.z, b2v); fma4(acc[r], a.w, b3v);
            }
        }

        // two-phase cross-wave reduce + fused epilogue out[rr]=dot(V4,T[q])
#pragma unroll
        for (int ph = 0; ph < 2; ++ph) {
            float* my = BsF + wv * 2048;
#pragma unroll
            for (int r8 = 0; r8 < 8; ++r8)
                *(float4*)(my + r8*256 + ln*4) = acc[ph*8 + r8];
            __syncthreads();
#pragma unroll
            for (int i = 0; i < 2; ++i) {
                const int rr8 = wv*2 + i;
                const int sIdx = ph*8 + rr8;
                const int rr = rows[sIdx];
                float p = 0.f;
                if (rr >= 0) {
                    float4 v        = *(const float4*)(BsF +        rr8*256 + ln*4);
                    const float4 p1 = *(const float4*)(BsF + 2048 + rr8*256 + ln*4);
                    const float4 p2 = *(const float4*)(BsF + 4096 + rr8*256 + ln*4);
                    const float4 p3 = *(const float4*)(BsF + 6144 + rr8*256 + ln*4);
                    v.x += p1.x + p2.x + p3.x; v.y += p1.y + p2.y + p3.y;
                    v.z += p1.z + p2.z + p3.z; v.w += p1.w + p2.w + p3.w;
                    const float4 tv = *(const float4*)(T + (size_t)qs[sIdx]*256 + ln*4);
                    p = fmaf(v.x, tv.x, fmaf(v.y, tv.y,
                        fmaf(v.z, tv.z, v.w * tv.w)));
                }
                p += __shfl_xor(p, 1);
                p += __shfl_xor(p, 2);
                p += __shfl_xor(p, 4);
                p += __shfl_xor(p, 8);
                p += __shfl_xor(p, 16);
                p += __shfl_xor(p, 32);
                if (ln == 0 && rr >= 0) out[rr] = p;
            }
            __syncthreads();
        }
    }
}

extern "C" void kernel_launch(void* const* d_in, const int* in_sizes, int n_in,
                              void* d_out, int out_size, void* d_ws, size_t ws_size,
                              hipStream_t stream) {
    const float* C0 = (const float*)d_in[0];
    const float* C1 = (const float*)d_in[1];
    const float* C2 = (const float*)d_in[2];
    const float* C3 = (const float*)d_in[3];
    const float* C4 = (const float*)d_in[4];
    const float* C5 = (const float*)d_in[5];
    const float* C6 = (const float*)d_in[6];
    const float* C7 = (const float*)d_in[7];
    const int* coords = (const int*)d_in[8];
    float* out = (float*)d_out;

    const int n = in_sizes[8] / 3;

    // workspace (~4.6 MB)
    float* P3   = (float*)d_ws;                       // 4096*256
    float* Tt   = P3 + 4096*256;                      // 512*256
    int*   perms = (int*)(Tt + 512*256);              // n
    int*   bases = perms + (size_t)n;                 // 9

    tables_kernel<<<321, 256, 0, stream>>>(
        C0, C1, C2, C3, C5, C6, C7, coords, n, perms, bases, P3, Tt);
    stage4_final_kernel<<<dim3(8, 32), 256, 0, stream>>>(
        P3, C4, Tt, coords, perms, bases, out);
}

// Round 7
// 115.858 us; speedup vs baseline: 1.0502x; 1.0502x over previous
//
#include <hip/hip_runtime.h>

// QTT 3D sampling, round 16: round-12 structure + register-streamed GEMM.
//   out[i] = P3[a_i] · U[d4_i*512 + q_i]   (round-11 reassociation)
//   K0 (32 blocks):  C4t[d4][s5][k] = C4[k][d4][s5]   (transpose; verified r12)
//   K1 (512 blocks): bx 0-255   P3 = C0·C1·C2·C3, block=(d0,d2pair,d3)
//                    bx 256-511 U[d4][q][k] = sum_s5 T[q][s5]*C4t[d4][s5][k],
//                               block=(d4,qtile16); 16 T rows rebuilt IN-SITU
//                               from C5/C6/C7 (no T table, no extra producer).
//     GEMM core (kgemm4): wave wv owns 4 full-K output rows; A rows broadcast
//     from LDS; B rows streamed global->VGPR, 2-deep ping-pong (8 in flight).
//     B is column-contiguous in BOTH paths: C3 rows (stride 2048) and C4t
//     rows (stride 256). No LDS B-staging, no cross-wave reduce, no main-loop
//     barriers. (Round-15 bug was streaming raw C4 = wrong contraction axis.)
//   K2 (512 blocks): out[i] = dot256(P3[a_i], U[...]), 2 samples/wave (r12).
// Core shapes: (r_l, 8, r_{l+1}), ranks 1,8,64,256,256,256,64,8,1.
// C_l[k][d][s] at C_l[k*8*r_out + d*r_out + s].

typedef unsigned int u32;

__device__ __forceinline__ void fma4(float4& c, float a, const float4& b) {
    c.x = fmaf(a, b.x, c.x); c.y = fmaf(a, b.y, c.y);
    c.z = fmaf(a, b.z, c.z); c.w = fmaf(a, b.w, c.w);
}
__device__ __forceinline__ int digit_of(int x, int y, int z, int sh) {
    return 4*((x>>sh)&1) + 2*((y>>sh)&1) + ((z>>sh)&1);
}

// ---------------- K0: C4 transpose (exact round-12 code) ---------------------
__global__ __launch_bounds__(256, 4) void prep_kernel(
    const float* __restrict__ C4, float* __restrict__ C4t)
{
    const int t = threadIdx.x;
    const int cb = blockIdx.x;
    const int d4 = cb >> 2, s5q = cb & 3;
#pragma unroll 8
    for (int j = 0; j < 64; ++j) {
        const int s5 = s5q*64 + j;
        C4t[(size_t)d4*65536 + (size_t)s5*256 + t] =
            C4[(size_t)t*2048 + d4*256 + s5];
    }
}

// 4-row x 256-col GEMM over K=256. B row k at Bg + k*rowStride (+ ln*4 per
// lane, columns contiguous); A rows r0..r0+3 broadcast from LDS. Barrier-free.
__device__ __forceinline__ void kgemm4(
    const float* __restrict__ Bg, int rowStride,
    const float (*As)[260], int r0, int ln,
    float4& acc0, float4& acc1, float4& acc2, float4& acc3)
{
    const float* gp = Bg + ln * 4;
    float4 bA0 = *(const float4*)(gp + (size_t)0*rowStride);
    float4 bA1 = *(const float4*)(gp + (size_t)1*rowStride);
    float4 bA2 = *(const float4*)(gp + (size_t)2*rowStride);
    float4 bA3 = *(const float4*)(gp + (size_t)3*rowStride);
    float4 bB0 = *(const float4*)(gp + (size_t)4*rowStride);
    float4 bB1 = *(const float4*)(gp + (size_t)5*rowStride);
    float4 bB2 = *(const float4*)(gp + (size_t)6*rowStride);
    float4 bB3 = *(const float4*)(gp + (size_t)7*rowStride);

#define QTT_COMP(b0, b1, b2, b3, kb)                                   \
    {   const float4 a0 = *(const float4*)&As[r0+0][(kb)];             \
        const float4 a1 = *(const float4*)&As[r0+1][(kb)];             \
        const float4 a2 = *(const float4*)&As[r0+2][(kb)];             \
        const float4 a3 = *(const float4*)&As[r0+3][(kb)];             \
        fma4(acc0, a0.x, b0); fma4(acc0, a0.y, b1);                    \
        fma4(acc0, a0.z, b2); fma4(acc0, a0.w, b3);                    \
        fma4(acc1, a1.x, b0); fma4(acc1, a1.y, b1);                    \
        fma4(acc1, a1.z, b2); fma4(acc1, a1.w, b3);                    \
        fma4(acc2, a2.x, b0); fma4(acc2, a2.y, b1);                    \
        fma4(acc2, a2.z, b2); fma4(acc2, a2.w, b3);                    \
        fma4(acc3, a3.x, b0); fma4(acc3, a3.y, b1);                    \
        fma4(acc3, a3.z, b2); fma4(acc3, a3.w, b3); }

#pragma unroll 1
    for (int s = 0; s < 32; ++s) {
        const int k0 = s * 8;
        QTT_COMP(bA0, bA1, bA2, bA3, k0);
        if (s < 31) {
            bA0 = *(const float4*)(gp + (size_t)(k0+ 8)*rowStride);
            bA1 = *(const float4*)(gp + (size_t)(k0+ 9)*rowStride);
            bA2 = *(const float4*)(gp + (size_t)(k0+10)*rowStride);
            bA3 = *(const float4*)(gp + (size_t)(k0+11)*rowStride);
        }
        QTT_COMP(bB0, bB1, bB2, bB3, k0 + 4);
        if (s < 31) {
            bB0 = *(const float4*)(gp + (size_t)(k0+12)*rowStride);
            bB1 = *(const float4*)(gp + (size_t)(k0+13)*rowStride);
            bB2 = *(const float4*)(gp + (size_t)(k0+14)*rowStride);
            bB3 = *(const float4*)(gp + (size_t)(k0+15)*rowStride);
        }
    }
#undef QTT_COMP
}

// ---------------- K1: dense P3 table + dense U table (in-situ T) -------------
__global__ __launch_bounds__(256, 2) void tables_kernel(
    const float* __restrict__ C0, const float* __restrict__ C1,
    const float* __restrict__ C2, const float* __restrict__ C3,
    const float* __restrict__ C4t, const float* __restrict__ C5,
    const float* __restrict__ C6, const float* __restrict__ C7,
    float* __restrict__ P3, float* __restrict__ U)
{
    __shared__ __align__(16) struct {
        float small[4][4][64];    // P3: per-wave v64 slice | U: S6s slices
        float As[16][260];
    } u;                          // ~20.7 KB
    const int t = threadIdx.x;
    const int ln = t & 63, wv = t >> 6;
    const int bx = blockIdx.x;

    float4 acc0 = make_float4(0,0,0,0), acc1 = make_float4(0,0,0,0);
    float4 acc2 = make_float4(0,0,0,0), acc3 = make_float4(0,0,0,0);

    if (bx < 256) {
        // ---- P3 block: (d0, d2pair, d3); wave handles 4 d1 rows ----
        const int d3 = bx & 7, d2p = (bx >> 3) & 3, d0 = bx >> 5;

        // per-wave v64 slice: small[wv][i][c] = v64[d1base+i][c]
        const int d1base = (wv & 1) * 4;
#pragma unroll
        for (int i = 0; i < 4; ++i) {
            float acc = 0.f;
#pragma unroll
            for (int r8 = 0; r8 < 8; ++r8)
                acc = fmaf(C0[d0*8 + r8],
                           C1[r8*512 + (d1base + i)*64 + ln], acc);
            u.small[wv][i][ln] = acc;
        }
        __syncthreads();

        // As rows wv*4..+3: As[r][k] = sum_j v64[d1(r)][j] * C2[j, d2, k]
        const int d2 = d2p*2 + (wv >> 1);
        {
            float4 a0 = make_float4(0,0,0,0), a1 = make_float4(0,0,0,0);
            float4 a2 = make_float4(0,0,0,0), a3 = make_float4(0,0,0,0);
            const float* c2base = C2 + d2*256 + ln*4;
#pragma unroll
            for (int j4 = 0; j4 < 16; ++j4) {
                const float4 v0 = *(const float4*)&u.small[wv][0][j4*4];
                const float4 v1 = *(const float4*)&u.small[wv][1][j4*4];
                const float4 v2 = *(const float4*)&u.small[wv][2][j4*4];
                const float4 v3 = *(const float4*)&u.small[wv][3][j4*4];
#define QTT_ASTEP(jj, comp)                                            \
                { const float4 c2 = *(const float4*)(c2base +          \
                      (size_t)(j4*4 + jj)*2048);                       \
                  fma4(a0, v0.comp, c2); fma4(a1, v1.comp, c2);        \
                  fma4(a2, v2.comp, c2); fma4(a3, v3.comp, c2); }
                QTT_ASTEP(0, x) QTT_ASTEP(1, y) QTT_ASTEP(2, z) QTT_ASTEP(3, w)
#undef QTT_ASTEP
            }
            *(float4*)&u.As[wv*4+0][ln*4] = a0;
            *(float4*)&u.As[wv*4+1][ln*4] = a1;
            *(float4*)&u.As[wv*4+2][ln*4] = a2;
            *(float4*)&u.As[wv*4+3][ln*4] = a3;
        }
        __syncthreads();

        kgemm4(C3 + d3*256, 2048, u.As, wv*4, ln, acc0, acc1, acc2, acc3);

        const int rb = d0*512 + d2*8 + d3;
        *(float4*)(P3 + (size_t)(rb + (d1base+0)*64)*256 + ln*4) = acc0;
        *(float4*)(P3 + (size_t)(rb + (d1base+1)*64)*256 + ln*4) = acc1;
        *(float4*)(P3 + (size_t)(rb + (d1base+2)*64)*256 + ln*4) = acc2;
        *(float4*)(P3 + (size_t)(rb + (d1base+3)*64)*256 + ln*4) = acc3;
    } else {
        // ---- U block: (d4, qtile); rows q = qtile*16 + r, r in [0,16) ----
        const int ub = bx - 256;
        const int qtile = ub & 31, d4 = ub >> 5;
        const int d5 = qtile >> 2;

        // this thread's C5 row (s5 = t): creg[j4] = C5[t, d5, j4*4..+3]
        float4 creg[16];
#pragma unroll
        for (int j4 = 0; j4 < 16; ++j4)
            creg[j4] = *(const float4*)(C5 + (size_t)t*512 + d5*64 + j4*4);

        // per-wave S6 slice: small[wv][i][s6] for combo r = wv*4+i
        // (q = qtile*16 + r => d6 = (qtile&3)*2 + (r>>3), d7 = r&7)
#pragma unroll
        for (int i = 0; i < 4; ++i) {
            const int r = wv*4 + i;
            const int d6 = (qtile & 3)*2 + (r >> 3), d7 = r & 7;
            float acc = 0.f;
#pragma unroll
            for (int jj = 0; jj < 8; ++jj)
                acc = fmaf(C6[ln*64 + d6*8 + jj], C7[jj*8 + d7], acc);
            u.small[wv][i][ln] = acc;
        }
        __syncthreads();

        // As[r][t] = T[qtile*16+r][s5=t] = dot64(C5[t,d5,:], S6[r])
#pragma unroll 1
        for (int r = 0; r < 16; ++r) {
            float acc = 0.f;
#pragma unroll
            for (int j4 = 0; j4 < 16; ++j4) {
                const float4 s6 = *(const float4*)&u.small[r >> 2][r & 3][j4*4];
                const float4 c5 = creg[j4];
                acc = fmaf(c5.x, s6.x, acc); acc = fmaf(c5.y, s6.y, acc);
                acc = fmaf(c5.z, s6.z, acc); acc = fmaf(c5.w, s6.w, acc);
            }
            u.As[r][t] = acc;
        }
        __syncthreads();

        // U[q][c] = sum_s5 As[r][s5] * C4t[d4][s5][c]  (contiguous rows, 256)
        kgemm4(C4t + (size_t)d4*65536, 256, u.As, wv*4, ln,
               acc0, acc1, acc2, acc3);

        const int rb = d4*512 + qtile*16 + wv*4;
        *(float4*)(U + (size_t)(rb + 0)*256 + ln*4) = acc0;
        *(float4*)(U + (size_t)(rb + 1)*256 + ln*4) = acc1;
        *(float4*)(U + (size_t)(rb + 2)*256 + ln*4) = acc2;
        *(float4*)(U + (size_t)(rb + 3)*256 + ln*4) = acc3;
    }
}

// ---------------- K2: per-sample dot(P3 row, U row), 2 samples/wave ----------
__global__ __launch_bounds__(256) void final_kernel(
    const float* __restrict__ P3, const float* __restrict__ U,
    const int* __restrict__ coords, int n, float* __restrict__ out)
{
    const int ln = threadIdx.x & 63, wv = threadIdx.x >> 6;
    const int s0 = blockIdx.x * 8 + wv * 2;

    float p[2] = {0.f, 0.f};
    int valid[2];
#pragma unroll
    for (int i = 0; i < 2; ++i) {
        const int s = s0 + i;
        valid[i] = (s < n);
        if (valid[i]) {
            const int x = coords[3*s], y = coords[3*s+1], z = coords[3*s+2];
            const int a  = digit_of(x,y,z,7)*512 + digit_of(x,y,z,6)*64
                         + digit_of(x,y,z,5)*8  + digit_of(x,y,z,4);
            const int d4 = digit_of(x,y,z,3);
            const int q  = digit_of(x,y,z,2)*64 + digit_of(x,y,z,1)*8
                         + digit_of(x,y,z,0);
            const float4 p4 = *(const float4*)(P3 + (size_t)a*256 + ln*4);
            const float4 u4 = *(const float4*)(U + (size_t)(d4*512 + q)*256 + ln*4);
            p[i] = fmaf(p4.x, u4.x, fmaf(p4.y, u4.y,
                   fmaf(p4.z, u4.z, p4.w * u4.w)));
        }
    }
#pragma unroll
    for (int m = 1; m <= 32; m <<= 1) {
        p[0] += __shfl_xor(p[0], m);
        p[1] += __shfl_xor(p[1], m);
    }
    if (ln == 0) {
        if (valid[0]) out[s0]     = p[0];
        if (valid[1]) out[s0 + 1] = p[1];
    }
}

extern "C" void kernel_launch(void* const* d_in, const int* in_sizes, int n_in,
                              void* d_out, int out_size, void* d_ws, size_t ws_size,
                              hipStream_t stream) {
    const float* C0 = (const float*)d_in[0];
    const float* C1 = (const float*)d_in[1];
    const float* C2 = (const float*)d_in[2];
    const float* C3 = (const float*)d_in[3];
    const float* C4 = (const float*)d_in[4];
    const float* C5 = (const float*)d_in[5];
    const float* C6 = (const float*)d_in[6];
    const float* C7 = (const float*)d_in[7];
    const int* coords = (const int*)d_in[8];
    float* out = (float*)d_out;

    const int n = in_sizes[8] / 3;

    // workspace (~10.5 MB)
    float* P3  = (float*)d_ws;                 // 4096*256
    float* U   = P3 + 4096*256;                // 4096*256
    float* C4t = U  + 4096*256;                // 8*256*256

    prep_kernel<<<32, 256, 0, stream>>>(C4, C4t);
    tables_kernel<<<512, 256, 0, stream>>>(
        C0, C1, C2, C3, C4t, C5, C6, C7, P3, U);
    final_kernel<<<(n + 7) / 8, 256, 0, stream>>>(P3, U, coords, n, out);
}